// Round 1
// baseline (390.764 us; speedup 1.0000x reference)
//
#include <hip/hip_runtime.h>

typedef __bf16 bf16x8 __attribute__((ext_vector_type(8)));
typedef float f32x4 __attribute__((ext_vector_type(4)));
typedef short short4v __attribute__((ext_vector_type(4)));

#define AS1 __attribute__((address_space(1)))
#define AS3 __attribute__((address_space(3)))
#define GLL16(g, l) __builtin_amdgcn_global_load_lds((const AS1 void*)(g), (AS3 void*)(l), 16, 0, 0)
#define MFMA16(a, b, c) __builtin_amdgcn_mfma_f32_16x16x32_bf16((a), (b), (c), 0, 0, 0)

__device__ __forceinline__ unsigned short f2bf(float f) {
  unsigned int u = __builtin_bit_cast(unsigned int, f);
  u = (u + 0x7fffu + ((u >> 16) & 1u)) >> 16;
  return (unsigned short)u;
}
__device__ __forceinline__ float bf2f(unsigned short s) {
  unsigned int u = ((unsigned int)s) << 16;
  return __builtin_bit_cast(float, u);
}

// ---------------- convert: f32 -> bf16 (x, concat weights, w_o) ----------------
__global__ void convert_kernel(const float* __restrict__ x,
                               const float* __restrict__ w_qt, const float* __restrict__ w_kt,
                               const float* __restrict__ w_qs, const float* __restrict__ w_ks,
                               const float* __restrict__ w_v, const float* __restrict__ w_o,
                               unsigned short* __restrict__ xb, unsigned short* __restrict__ wcat,
                               unsigned short* __restrict__ wob) {
  const int NX = 4096 * 1024, NW = 3072 * 1024, NO = 1024 * 1024;
  int stride = gridDim.x * blockDim.x;
  for (int i = blockIdx.x * blockDim.x + threadIdx.x; i < NX + NW + NO; i += stride) {
    if (i < NX) {
      xb[i] = f2bf(x[i]);
    } else if (i < NX + NW) {
      int j = i - NX;
      int n = j >> 10, k = j & 1023;
      const float* src;
      if (n < 256)        src = w_qt + n * 1024;
      else if (n < 1024)  src = w_qs + (n - 256) * 1024;
      else if (n < 1280)  src = w_kt + (n - 1024) * 1024;
      else if (n < 2048)  src = w_ks + (n - 1280) * 1024;
      else                src = w_v + (n - 2048) * 1024;
      wcat[j] = f2bf(src[k]);
    } else {
      int j = i - NX - NW;
      wob[j] = f2bf(w_o[j]);
    }
  }
}

// ---------------- GEMM 1: X(4096x1024) * Wcat(3072x1024)^T -> Q,K,Vt ----------------
__global__ __launch_bounds__(256) void gemm_qkv(const unsigned short* __restrict__ A,
                                                const unsigned short* __restrict__ Bw,
                                                unsigned short* __restrict__ qb,
                                                unsigned short* __restrict__ kb,
                                                unsigned short* __restrict__ vt) {
  __shared__ unsigned short As[128 * 32];
  __shared__ unsigned short Bs[128 * 32];
  const int t = threadIdx.x;
  const int lane = t & 63, wid = t >> 6;
  const int wm = wid >> 1, wn = wid & 1;
  const int lr = lane & 15, lg = lane >> 4;
  const int m0 = blockIdx.x * 128, n0 = blockIdx.y * 128;
  const int K = 1024;
  f32x4 acc[4][4] = {};
  const unsigned short* gA0 = A + (m0 + (t >> 2)) * K + (t & 3) * 8;
  const unsigned short* gB0 = Bw + (n0 + (t >> 2)) * K + (t & 3) * 8;
  char* lA = (char*)As + wid * 1024;
  char* lB = (char*)Bs + wid * 1024;
  for (int k0 = 0; k0 < K; k0 += 32) {
    __syncthreads();
    GLL16(gA0 + k0, lA);
    GLL16(gA0 + 64 * K + k0, lA + 4096);
    GLL16(gB0 + k0, lB);
    GLL16(gB0 + 64 * K + k0, lB + 4096);
    __syncthreads();
    bf16x8 af[4], bfr[4];
#pragma unroll
    for (int i = 0; i < 4; ++i) {
      af[i] = *(const bf16x8*)&As[(wm * 64 + i * 16 + lr) * 32 + lg * 8];
      bfr[i] = *(const bf16x8*)&Bs[(wn * 64 + i * 16 + lr) * 32 + lg * 8];
    }
#pragma unroll
    for (int i = 0; i < 4; ++i)
#pragma unroll
      for (int j = 0; j < 4; ++j)
        acc[i][j] = MFMA16(af[i], bfr[j], acc[i][j]);
  }
  // epilogue: scatter into Q (B,H,L,64), K (B,H,L,64), Vt (B,H,64,L)
#pragma unroll
  for (int i = 0; i < 4; ++i) {
#pragma unroll
    for (int j = 0; j < 4; ++j) {
      int n = n0 + wn * 64 + j * 16 + lr;
      int mb = m0 + wm * 64 + i * 16 + lg * 4;
      f32x4 v = acc[i][j];
      if (n < 2048) {
        unsigned short* dst = (n < 1024) ? qb : kb;
        int nn = n & 1023;
        int h = nn >> 6, d = nn & 63;
#pragma unroll
        for (int r = 0; r < 4; ++r) {
          int m = mb + r;
          int b = m >> 11, l = m & 2047;
          dst[((b * 16 + h) * 2048 + l) * 64 + d] = f2bf(v[r]);
        }
      } else {
        int nn = n - 2048;
        int h = nn >> 6, d = nn & 63;
        int b = mb >> 11, l = mb & 2047;
        short4v pk;
        pk[0] = (short)f2bf(v[0]); pk[1] = (short)f2bf(v[1]);
        pk[2] = (short)f2bf(v[2]); pk[3] = (short)f2bf(v[3]);
        *(short4v*)&vt[((b * 16 + h) * 64 + d) * 2048 + l] = pk;
      }
    }
  }
}

// ---------------- attention: scores + softmax + probs write + PV ----------------
__global__ __launch_bounds__(256) void attn_kernel(const unsigned short* __restrict__ qb,
                                                   const unsigned short* __restrict__ kb,
                                                   const unsigned short* __restrict__ vt,
                                                   const float* __restrict__ mask,
                                                   const float* __restrict__ w_sigma,
                                                   float* __restrict__ probs,
                                                   unsigned short* __restrict__ ao) {
  extern __shared__ char smem[];            // 65536 B: ebuf[16][2048] bf16 (XOR-swizzled)
  __shared__ float rowsum4[64];
  __shared__ float rinv[16];
  const int t = threadIdx.x;
  const int lane = t & 63, wid = t >> 6;
  const int lr = lane & 15, lg = lane >> 4;
  const int q0 = blockIdx.x * 16;
  const int bh = blockIdx.y;
  const int b = bh >> 4, h = bh & 15;
  const float sigma = 1.0f / (1.0f + __expf(-w_sigma[0]));
  const float fac = (h < 4) ? (-sigma * 0.125f) : 0.125f;
  const float* maskb = mask + b * 2048;

  const unsigned short* qrow = qb + ((bh * 2048) + q0 + lr) * 64 + lg * 8;
  bf16x8 aq0 = *(const bf16x8*)qrow;
  bf16x8 aq1 = *(const bf16x8*)(qrow + 32);

  float rs[4] = {0.f, 0.f, 0.f, 0.f};
#pragma unroll 4
  for (int it = 0; it < 32; ++it) {
    int kc = it * 64 + wid * 16;
    const unsigned short* krow = kb + ((bh * 2048) + kc + lr) * 64 + lg * 8;
    bf16x8 bk0 = *(const bf16x8*)krow;
    bf16x8 bk1 = *(const bf16x8*)(krow + 32);
    f32x4 acc = {};
    acc = MFMA16(aq0, bk0, acc);
    acc = MFMA16(aq1, bk1, acc);
    int col = kc + lr;
    float mval = maskb[col];
#pragma unroll
    for (int r = 0; r < 4; ++r) {
      int row = lg * 4 + r;
      float e = __expf(acc[r] * fac + mval);
      rs[r] += e;
      int off = (row * 4096 + col * 2) ^ ((row & 7) << 4);
      *(unsigned short*)(smem + off) = f2bf(e);
    }
  }
#pragma unroll
  for (int o = 1; o < 16; o <<= 1)
#pragma unroll
    for (int r = 0; r < 4; ++r) rs[r] += __shfl_xor(rs[r], o);
  if (lr == 0) {
#pragma unroll
    for (int r = 0; r < 4; ++r) rowsum4[wid * 16 + lg * 4 + r] = rs[r];
  }
  __syncthreads();
  if (t < 16) rinv[t] = 1.0f / (rowsum4[t] + rowsum4[16 + t] + rowsum4[32 + t] + rowsum4[48 + t]);
  __syncthreads();

  // PV: out(16x64) = P(16x2048) * V(2048x64); wave wid owns d-slice [wid*16, wid*16+16)
  f32x4 p0 = {}, p1 = {};
  const unsigned short* vrow = vt + ((bh * 64) + wid * 16 + lr) * 2048;
#pragma unroll 4
  for (int k0 = 0; k0 < 2048; k0 += 64) {
    int offA0 = (lr * 4096 + (k0 + lg * 8) * 2) ^ ((lr & 7) << 4);
    int offA1 = (lr * 4096 + (k0 + 32 + lg * 8) * 2) ^ ((lr & 7) << 4);
    bf16x8 a0 = *(const bf16x8*)(smem + offA0);
    bf16x8 a1 = *(const bf16x8*)(smem + offA1);
    bf16x8 b0 = *(const bf16x8*)(vrow + k0 + lg * 8);
    bf16x8 b1 = *(const bf16x8*)(vrow + k0 + 32 + lg * 8);
    p0 = MFMA16(a0, b0, p0);
    p1 = MFMA16(a1, b1, p1);
  }
  {
    int d = wid * 16 + lr;
#pragma unroll
    for (int r = 0; r < 4; ++r) {
      int row = lg * 4 + r;
      float o = (p0[r] + p1[r]) * rinv[row];
      ao[((b * 2048) + q0 + row) * 1024 + h * 64 + d] = f2bf(o);
    }
  }

  // probs write: normalized, fully coalesced f32x4 stores
  float* pout = probs + ((bh * 2048) + q0) * (long long)2048;
  for (int r = 0; r < 16; ++r) {
    int c0 = t * 8;
    int off = (r * 4096 + c0 * 2) ^ ((r & 7) << 4);
    bf16x8 ev = *(const bf16x8*)(smem + off);
    const unsigned short* evu = (const unsigned short*)&ev;
    float inv = rinv[r];
    float* dst = pout + r * 2048 + c0;
    f32x4 o0 = { bf2f(evu[0]) * inv, bf2f(evu[1]) * inv, bf2f(evu[2]) * inv, bf2f(evu[3]) * inv };
    f32x4 o1 = { bf2f(evu[4]) * inv, bf2f(evu[5]) * inv, bf2f(evu[6]) * inv, bf2f(evu[7]) * inv };
    *(f32x4*)dst = o0;
    *(f32x4*)(dst + 4) = o1;
  }
}

// ---------------- GEMM 2: AO(4096x1024) * Wo(1024x1024)^T -> out f32 ----------------
__global__ __launch_bounds__(256) void gemm_oproj(const unsigned short* __restrict__ A,
                                                  const unsigned short* __restrict__ Bw,
                                                  float* __restrict__ out) {
  __shared__ unsigned short As[128 * 32];
  __shared__ unsigned short Bs[128 * 32];
  const int t = threadIdx.x;
  const int lane = t & 63, wid = t >> 6;
  const int wm = wid >> 1, wn = wid & 1;
  const int lr = lane & 15, lg = lane >> 4;
  const int m0 = blockIdx.x * 128, n0 = blockIdx.y * 128;
  const int K = 1024;
  f32x4 acc[4][4] = {};
  const unsigned short* gA0 = A + (m0 + (t >> 2)) * K + (t & 3) * 8;
  const unsigned short* gB0 = Bw + (n0 + (t >> 2)) * K + (t & 3) * 8;
  char* lA = (char*)As + wid * 1024;
  char* lB = (char*)Bs + wid * 1024;
  for (int k0 = 0; k0 < K; k0 += 32) {
    __syncthreads();
    GLL16(gA0 + k0, lA);
    GLL16(gA0 + 64 * K + k0, lA + 4096);
    GLL16(gB0 + k0, lB);
    GLL16(gB0 + 64 * K + k0, lB + 4096);
    __syncthreads();
    bf16x8 af[4], bfr[4];
#pragma unroll
    for (int i = 0; i < 4; ++i) {
      af[i] = *(const bf16x8*)&As[(wm * 64 + i * 16 + lr) * 32 + lg * 8];
      bfr[i] = *(const bf16x8*)&Bs[(wn * 64 + i * 16 + lr) * 32 + lg * 8];
    }
#pragma unroll
    for (int i = 0; i < 4; ++i)
#pragma unroll
      for (int j = 0; j < 4; ++j)
        acc[i][j] = MFMA16(af[i], bfr[j], acc[i][j]);
  }
#pragma unroll
  for (int i = 0; i < 4; ++i) {
#pragma unroll
    for (int j = 0; j < 4; ++j) {
      int n = n0 + wn * 64 + j * 16 + lr;
      int mb = m0 + wm * 64 + i * 16 + lg * 4;
#pragma unroll
      for (int r = 0; r < 4; ++r)
        out[(mb + r) * 1024 + n] = acc[i][j][r];
    }
  }
}

extern "C" void kernel_launch(void* const* d_in, const int* in_sizes, int n_in,
                              void* d_out, int out_size, void* d_ws, size_t ws_size,
                              hipStream_t stream) {
  const float* x       = (const float*)d_in[0];
  const float* amask   = (const float*)d_in[1];
  const float* w_qt    = (const float*)d_in[2];
  const float* w_kt    = (const float*)d_in[3];
  const float* w_qs    = (const float*)d_in[4];
  const float* w_ks    = (const float*)d_in[5];
  const float* w_sigma = (const float*)d_in[6];
  const float* w_v     = (const float*)d_in[7];
  const float* w_o     = (const float*)d_in[8];

  char* ws = (char*)d_ws;
  unsigned short* xb   = (unsigned short*)ws;                    // 8 MB
  unsigned short* wcat = (unsigned short*)(ws + 8388608);        // 6 MB
  unsigned short* wob  = (unsigned short*)(ws + 14680064);       // 2 MB
  unsigned short* qb   = (unsigned short*)(ws + 16777216);       // 8 MB
  unsigned short* kb   = (unsigned short*)(ws + 25165824);       // 8 MB
  unsigned short* vt   = (unsigned short*)(ws + 33554432);       // 8 MB
  unsigned short* ao   = (unsigned short*)(ws + 41943040);       // 8 MB

  float* outp = (float*)d_out;
  float* probs = outp + 4194304;

  hipFuncSetAttribute((const void*)attn_kernel, hipFuncAttributeMaxDynamicSharedMemorySize, 65536);

  convert_kernel<<<2048, 256, 0, stream>>>(x, w_qt, w_kt, w_qs, w_ks, w_v, w_o, xb, wcat, wob);
  gemm_qkv<<<dim3(32, 24), 256, 0, stream>>>(xb, wcat, qb, kb, vt);
  attn_kernel<<<dim3(128, 32), 256, 65536, stream>>>(qb, kb, vt, amask, w_sigma, probs, ao);
  gemm_oproj<<<dim3(32, 8), 256, 0, stream>>>(ao, wob, outp);
}

// Round 2
// 340.519 us; speedup vs baseline: 1.1476x; 1.1476x over previous
//
#include <hip/hip_runtime.h>

typedef __bf16 bf16x8 __attribute__((ext_vector_type(8)));
typedef float f32x4 __attribute__((ext_vector_type(4)));
typedef short short4v __attribute__((ext_vector_type(4)));
typedef unsigned short ushort8 __attribute__((ext_vector_type(8)));

#define AS1 __attribute__((address_space(1)))
#define AS3 __attribute__((address_space(3)))
#define GLL16(g, l) __builtin_amdgcn_global_load_lds((const AS1 void*)(g), (AS3 void*)(l), 16, 0, 0)
#define MFMA16(a, b, c) __builtin_amdgcn_mfma_f32_16x16x32_bf16((a), (b), (c), 0, 0, 0)

__device__ __forceinline__ unsigned short f2bf(float f) {
  unsigned int u = __builtin_bit_cast(unsigned int, f);
  u = (u + 0x7fffu + ((u >> 16) & 1u)) >> 16;
  return (unsigned short)u;
}

// ---------------- convert: f32 -> bf16 (x, concat weights, w_o) ----------------
__global__ void convert_kernel(const float* __restrict__ x,
                               const float* __restrict__ w_qt, const float* __restrict__ w_kt,
                               const float* __restrict__ w_qs, const float* __restrict__ w_ks,
                               const float* __restrict__ w_v, const float* __restrict__ w_o,
                               unsigned short* __restrict__ xb, unsigned short* __restrict__ wcat,
                               unsigned short* __restrict__ wob) {
  const int NX = 4096 * 1024, NW = 3072 * 1024, NO = 1024 * 1024;
  int stride = gridDim.x * blockDim.x;
  for (int i = blockIdx.x * blockDim.x + threadIdx.x; i < NX + NW + NO; i += stride) {
    if (i < NX) {
      xb[i] = f2bf(x[i]);
    } else if (i < NX + NW) {
      int j = i - NX;
      int n = j >> 10, k = j & 1023;
      const float* src;
      if (n < 256)        src = w_qt + n * 1024;
      else if (n < 1024)  src = w_qs + (n - 256) * 1024;
      else if (n < 1280)  src = w_kt + (n - 1024) * 1024;
      else if (n < 2048)  src = w_ks + (n - 1280) * 1024;
      else                src = w_v + (n - 2048) * 1024;
      wcat[j] = f2bf(src[k]);
    } else {
      int j = i - NX - NW;
      wob[j] = f2bf(w_o[j]);
    }
  }
}

// ---------------- GEMM 1: X(4096x1024) * Wcat(3072x1024)^T -> Q,K,Vt ----------------
__global__ __launch_bounds__(256) void gemm_qkv(const unsigned short* __restrict__ A,
                                                const unsigned short* __restrict__ Bw,
                                                unsigned short* __restrict__ qb,
                                                unsigned short* __restrict__ kb,
                                                unsigned short* __restrict__ vt) {
  __shared__ unsigned short As[128 * 32];
  __shared__ unsigned short Bs[128 * 32];
  const int t = threadIdx.x;
  const int lane = t & 63, wid = t >> 6;
  const int wm = wid >> 1, wn = wid & 1;
  const int lr = lane & 15, lg = lane >> 4;
  const int m0 = blockIdx.x * 128, n0 = blockIdx.y * 128;
  const int K = 1024;
  f32x4 acc[4][4] = {};
  const unsigned short* gA0 = A + (m0 + (t >> 2)) * K + (t & 3) * 8;
  const unsigned short* gB0 = Bw + (n0 + (t >> 2)) * K + (t & 3) * 8;
  char* lA = (char*)As + wid * 1024;
  char* lB = (char*)Bs + wid * 1024;
  for (int k0 = 0; k0 < K; k0 += 32) {
    __syncthreads();
    GLL16(gA0 + k0, lA);
    GLL16(gA0 + 64 * K + k0, lA + 4096);
    GLL16(gB0 + k0, lB);
    GLL16(gB0 + 64 * K + k0, lB + 4096);
    __syncthreads();
    bf16x8 af[4], bfr[4];
#pragma unroll
    for (int i = 0; i < 4; ++i) {
      af[i] = *(const bf16x8*)&As[(wm * 64 + i * 16 + lr) * 32 + lg * 8];
      bfr[i] = *(const bf16x8*)&Bs[(wn * 64 + i * 16 + lr) * 32 + lg * 8];
    }
#pragma unroll
    for (int i = 0; i < 4; ++i)
#pragma unroll
      for (int j = 0; j < 4; ++j)
        acc[i][j] = MFMA16(af[i], bfr[j], acc[i][j]);
  }
  // epilogue: scatter into Q (B,H,L,64), K (B,H,L,64), Vt (B,H,64,L)
#pragma unroll
  for (int i = 0; i < 4; ++i) {
#pragma unroll
    for (int j = 0; j < 4; ++j) {
      int n = n0 + wn * 64 + j * 16 + lr;
      int mb = m0 + wm * 64 + i * 16 + lg * 4;
      f32x4 v = acc[i][j];
      if (n < 2048) {
        unsigned short* dst = (n < 1024) ? qb : kb;
        int nn = n & 1023;
        int h = nn >> 6, d = nn & 63;
#pragma unroll
        for (int r = 0; r < 4; ++r) {
          int m = mb + r;
          int b = m >> 11, l = m & 2047;
          dst[((b * 16 + h) * 2048 + l) * 64 + d] = f2bf(v[r]);
        }
      } else {
        int nn = n - 2048;
        int h = nn >> 6, d = nn & 63;
        int b = mb >> 11, l = mb & 2047;
        short4v pk;
        pk[0] = (short)f2bf(v[0]); pk[1] = (short)f2bf(v[1]);
        pk[2] = (short)f2bf(v[2]); pk[3] = (short)f2bf(v[3]);
        *(short4v*)&vt[((b * 16 + h) * 64 + d) * 2048 + l] = pk;
      }
    }
  }
}

// ---------------- attention v2: two-pass recompute, direct probs stream ----------------
// Block: 32 q-rows, 4 waves; wave w owns contiguous k-range [w*512, w*512+512).
__global__ __launch_bounds__(256, 4) void attn_kernel(const unsigned short* __restrict__ qb,
                                                      const unsigned short* __restrict__ kb,
                                                      const unsigned short* __restrict__ vt,
                                                      const float* __restrict__ mask,
                                                      const float* __restrict__ w_sigma,
                                                      float* __restrict__ probs,
                                                      unsigned short* __restrict__ ao) {
  __shared__ __align__(16) unsigned short ebuf[2][4][1280];  // [dbuf][wave][32 rows * 40 pad] bf16
  __shared__ __align__(16) float pvacc[2048];                // 32 q x 64 d partial-PV accumulator
  __shared__ float psum[4][32];
  __shared__ float rinv[32];
  const int t = threadIdx.x;
  const int lane = t & 63, w = t >> 6;
  const int lr = lane & 15, lg = lane >> 4;
  const int q0 = blockIdx.x * 32;
  const int bh = blockIdx.y;
  const int b = bh >> 4, h = bh & 15;
  const float sigma = 1.0f / (1.0f + __expf(-w_sigma[0]));
  const float fac = (h < 4) ? (-sigma * 0.125f) : 0.125f;
  const float* maskb = mask + b * 2048;
  const int kbase = w * 512;

  for (int i = t; i < 2048; i += 256) pvacc[i] = 0.0f;

  // Q fragments, held for the whole kernel
  bf16x8 aq[2][2];
#pragma unroll
  for (int qt = 0; qt < 2; ++qt) {
    const unsigned short* qp = qb + ((bh * 2048) + q0 + qt * 16 + lr) * 64 + lg * 8;
    aq[qt][0] = *(const bf16x8*)qp;
    aq[qt][1] = *(const bf16x8*)(qp + 32);
  }

  // ---- pass 1: rowsums only ----
  float rs[2][4] = {};
  for (int c = 0; c < 16; ++c) {
    int kc = kbase + c * 32;
#pragma unroll
    for (int kt = 0; kt < 2; ++kt) {
      int col = kc + kt * 16 + lr;
      const unsigned short* kp = kb + ((bh * 2048) + col) * 64 + lg * 8;
      bf16x8 b0 = *(const bf16x8*)kp;
      bf16x8 b1 = *(const bf16x8*)(kp + 32);
      float mv = maskb[col];
#pragma unroll
      for (int qt = 0; qt < 2; ++qt) {
        f32x4 acc = {};
        acc = MFMA16(aq[qt][0], b0, acc);
        acc = MFMA16(aq[qt][1], b1, acc);
#pragma unroll
        for (int r = 0; r < 4; ++r) rs[qt][r] += __expf(acc[r] * fac + mv);
      }
    }
  }
#pragma unroll
  for (int o = 1; o < 16; o <<= 1)
#pragma unroll
    for (int qt = 0; qt < 2; ++qt)
#pragma unroll
      for (int r = 0; r < 4; ++r) rs[qt][r] += __shfl_xor(rs[qt][r], o);
  if (lr == 0) {
#pragma unroll
    for (int qt = 0; qt < 2; ++qt)
#pragma unroll
      for (int r = 0; r < 4; ++r) psum[w][qt * 16 + lg * 4 + r] = rs[qt][r];
  }
  __syncthreads();
  if (t < 32) rinv[t] = 1.0f / (psum[0][t] + psum[1][t] + psum[2][t] + psum[3][t]);
  __syncthreads();

  float rv[2][4];
#pragma unroll
  for (int qt = 0; qt < 2; ++qt)
#pragma unroll
    for (int r = 0; r < 4; ++r) rv[qt][r] = rinv[qt * 16 + lg * 4 + r];

  // ---- pass 2: recompute, stream probs, accumulate PV ----
  float* pp = probs + (long long)(bh * 2048 + q0) * 2048;
  f32x4 pv[2][4] = {};
  for (int c = 0; c < 16; ++c) {
    int kc = kbase + c * 32;
    unsigned short* eb = &ebuf[c & 1][w][0];
#pragma unroll
    for (int kt = 0; kt < 2; ++kt) {
      int col = kc + kt * 16 + lr;
      const unsigned short* kp = kb + ((bh * 2048) + col) * 64 + lg * 8;
      bf16x8 b0 = *(const bf16x8*)kp;
      bf16x8 b1 = *(const bf16x8*)(kp + 32);
      float mv = maskb[col];
#pragma unroll
      for (int qt = 0; qt < 2; ++qt) {
        f32x4 acc = {};
        acc = MFMA16(aq[qt][0], b0, acc);
        acc = MFMA16(aq[qt][1], b1, acc);
#pragma unroll
        for (int r = 0; r < 4; ++r) {
          float ev = __expf(acc[r] * fac + mv);
          eb[(qt * 16 + lg * 4 + r) * 40 + kt * 16 + lr] = f2bf(ev);
          __builtin_nontemporal_store(ev * rv[qt][r],
              &pp[(qt * 16 + lg * 4 + r) * 2048 + kt * 16 + lr + kc]);
        }
      }
    }
    asm volatile("s_waitcnt lgkmcnt(0)" ::: "memory");
    bf16x8 pa[2];
#pragma unroll
    for (int qt = 0; qt < 2; ++qt)
      pa[qt] = *(const bf16x8*)&eb[(qt * 16 + lr) * 40 + lg * 8];
#pragma unroll
    for (int dt = 0; dt < 4; ++dt) {
      const unsigned short* vp = vt + ((bh * 64) + dt * 16 + lr) * 2048 + kc + lg * 8;
      bf16x8 bv = *(const bf16x8*)vp;
      pv[0][dt] = MFMA16(pa[0], bv, pv[0][dt]);
      pv[1][dt] = MFMA16(pa[1], bv, pv[1][dt]);
    }
  }

  // merge PV partials across waves
#pragma unroll
  for (int qt = 0; qt < 2; ++qt)
#pragma unroll
    for (int dt = 0; dt < 4; ++dt)
#pragma unroll
      for (int r = 0; r < 4; ++r)
        atomicAdd(&pvacc[(qt * 16 + lg * 4 + r) * 64 + dt * 16 + lr], pv[qt][dt][r]);
  __syncthreads();

  // ao write: 256 threads cover 32 rows x 64 d, coalesced 128B rows
  {
    int row = t >> 3, c8 = (t & 7) * 8;
    f32x4 v0 = *(const f32x4*)&pvacc[row * 64 + c8];
    f32x4 v1 = *(const f32x4*)&pvacc[row * 64 + c8 + 4];
    float ri = rinv[row];
    ushort8 o;
#pragma unroll
    for (int i = 0; i < 4; ++i) {
      o[i] = f2bf(v0[i] * ri);
      o[i + 4] = f2bf(v1[i] * ri);
    }
    *(ushort8*)&ao[((b * 2048) + q0 + row) * 1024 + h * 64 + c8] = o;
  }
}

// ---------------- GEMM 2: AO(4096x1024) * Wo(1024x1024)^T -> out f32 ----------------
__global__ __launch_bounds__(256) void gemm_oproj(const unsigned short* __restrict__ A,
                                                  const unsigned short* __restrict__ Bw,
                                                  float* __restrict__ out) {
  __shared__ unsigned short As[128 * 32];
  __shared__ unsigned short Bs[128 * 32];
  const int t = threadIdx.x;
  const int lane = t & 63, wid = t >> 6;
  const int wm = wid >> 1, wn = wid & 1;
  const int lr = lane & 15, lg = lane >> 4;
  const int m0 = blockIdx.x * 128, n0 = blockIdx.y * 128;
  const int K = 1024;
  f32x4 acc[4][4] = {};
  const unsigned short* gA0 = A + (m0 + (t >> 2)) * K + (t & 3) * 8;
  const unsigned short* gB0 = Bw + (n0 + (t >> 2)) * K + (t & 3) * 8;
  char* lA = (char*)As + wid * 1024;
  char* lB = (char*)Bs + wid * 1024;
  for (int k0 = 0; k0 < K; k0 += 32) {
    __syncthreads();
    GLL16(gA0 + k0, lA);
    GLL16(gA0 + 64 * K + k0, lA + 4096);
    GLL16(gB0 + k0, lB);
    GLL16(gB0 + 64 * K + k0, lB + 4096);
    __syncthreads();
    bf16x8 af[4], bfr[4];
#pragma unroll
    for (int i = 0; i < 4; ++i) {
      af[i] = *(const bf16x8*)&As[(wm * 64 + i * 16 + lr) * 32 + lg * 8];
      bfr[i] = *(const bf16x8*)&Bs[(wn * 64 + i * 16 + lr) * 32 + lg * 8];
    }
#pragma unroll
    for (int i = 0; i < 4; ++i)
#pragma unroll
      for (int j = 0; j < 4; ++j)
        acc[i][j] = MFMA16(af[i], bfr[j], acc[i][j]);
  }
#pragma unroll
  for (int i = 0; i < 4; ++i) {
#pragma unroll
    for (int j = 0; j < 4; ++j) {
      int n = n0 + wn * 64 + j * 16 + lr;
      int mb = m0 + wm * 64 + i * 16 + lg * 4;
#pragma unroll
      for (int r = 0; r < 4; ++r)
        out[(mb + r) * 1024 + n] = acc[i][j][r];
    }
  }
}

extern "C" void kernel_launch(void* const* d_in, const int* in_sizes, int n_in,
                              void* d_out, int out_size, void* d_ws, size_t ws_size,
                              hipStream_t stream) {
  const float* x       = (const float*)d_in[0];
  const float* amask   = (const float*)d_in[1];
  const float* w_qt    = (const float*)d_in[2];
  const float* w_kt    = (const float*)d_in[3];
  const float* w_qs    = (const float*)d_in[4];
  const float* w_ks    = (const float*)d_in[5];
  const float* w_sigma = (const float*)d_in[6];
  const float* w_v     = (const float*)d_in[7];
  const float* w_o     = (const float*)d_in[8];

  char* ws = (char*)d_ws;
  unsigned short* xb   = (unsigned short*)ws;                    // 8 MB
  unsigned short* wcat = (unsigned short*)(ws + 8388608);        // 6 MB
  unsigned short* wob  = (unsigned short*)(ws + 14680064);       // 2 MB
  unsigned short* qb   = (unsigned short*)(ws + 16777216);       // 8 MB
  unsigned short* kb   = (unsigned short*)(ws + 25165824);       // 8 MB
  unsigned short* vt   = (unsigned short*)(ws + 33554432);       // 8 MB
  unsigned short* ao   = (unsigned short*)(ws + 41943040);       // 8 MB

  float* outp = (float*)d_out;
  float* probs = outp + 4194304;

  convert_kernel<<<2048, 256, 0, stream>>>(x, w_qt, w_kt, w_qs, w_ks, w_v, w_o, xb, wcat, wob);
  gemm_qkv<<<dim3(32, 24), 256, 0, stream>>>(xb, wcat, qb, kb, vt);
  attn_kernel<<<dim3(64, 32), 256, 0, stream>>>(qb, kb, vt, amask, w_sigma, probs, ao);
  gemm_oproj<<<dim3(32, 8), 256, 0, stream>>>(ao, wob, outp);
}